// Round 3
// baseline (203.781 us; speedup 1.0000x reference)
//
#include <hip/hip_runtime.h>

#define NN 192
#define BX 48
#define BZ 8
#define YC 8
#define ROWS (BZ + 2)                 // z rows per plane incl. halo
#define PLANE_F (2 * ROWS * NN)       // floats per plane buffer (I+J) = 3840
#define NTHR (BX * BZ)                // 384

// Raw (un-halved) gradients: rawG = 2*trueG; 0.5^2 factors cancel in ngf if
// EPS^2 (0.01) is replaced by 4*EPS^2 = 0.04.
//
// Structure: block = (x: all 192, z-tile: 8, y-chunk: 8). March y. Per step,
// stage the y+1 plane (10 z rows x 192 x {I,J}, z/y clamping baked in) into a
// double-buffered LDS plane; fold it into rotating register slots
// (sa = sum_dz xdiff, sb = sum_dz xbox, tb = xbox(z+1)-xbox(z-1)); compute
// voxels once 3 slots are live. One barrier per step; next plane's global
// loads are issued after the barrier and consumed at the next step's ds_write.
__global__ __launch_bounds__(NTHR, 3) void ngf_kernel(const float* __restrict__ I,
                                                      const float* __restrict__ J,
                                                      const float* __restrict__ M,
                                                      float* __restrict__ out) {
    __shared__ float lds[2 * PLANE_F];   // 30720 B

    const int tx = threadIdx.x;          // x group: x0 = 4*tx
    const int tz = threadIdx.y;
    const int flat = tz * BX + tx;
    const int x0 = tx * 4;
    const int xm = (tx == 0) ? 0 : (x0 - 1);        // clamped x-1
    const int xp = (tx == BX - 1) ? (NN - 1) : (x0 + 4); // clamped x+4
    const int z0 = blockIdx.y * BZ;
    const int z = z0 + tz;
    const int ybase = blockIdx.x * YC;

    // ---- staging assignment (loop-invariant): plane = 960 float4 elements
    // e in [0,960): arr = e/480, zr = (e%480)/48, xg = e%48
    // LDS float offset = e*4  ->  layout [arr][zr][x], pitch NN, arr stride ROWS*NN
    const float* sp[3];
    int gi[3];   // global float index, invariant part: zClamp*NN*NN + xg*4
    int le[3];   // lds float offset
    {
        const int eidx[3] = {flat, flat + NTHR, flat + 2 * NTHR};
#pragma unroll
        for (int j = 0; j < 3; ++j) {
            const int e = eidx[j];
            const int arr = e / (ROWS * BX);                 // /480
            const int rem = e - arr * (ROWS * BX);
            const int zr = rem / BX;
            const int xg = rem - zr * BX;
            int zc = z0 - 1 + zr;
            zc = zc < 0 ? 0 : (zc > NN - 1 ? NN - 1 : zc);
            sp[j] = arr ? J : I;
            gi[j] = zc * NN * NN + xg * 4;
            le[j] = e * 4;
        }
    }
    const bool has3 = (flat < 960 - 2 * NTHR);   // flat < 192

    // ---- seed: load plane k=0 (y = ybase-1, clamped)
    float4 r0, r1, r2;
    {
        const int yc = (ybase == 0) ? 0 : (ybase - 1);
        const int yr = yc * NN;
        r0 = *(const float4*)(sp[0] + gi[0] + yr);
        r1 = *(const float4*)(sp[1] + gi[1] + yr);
        if (has3) r2 = *(const float4*)(sp[2] + gi[2] + yr);
    }

    float sa[2][3][4], sb[2][3][4], tb[2][3][4];
    float acc = 0.0f;
    float4 m_cur = make_float4(0.f, 0.f, 0.f, 0.f);

#pragma unroll
    for (int k = 0; k < YC + 2; ++k) {
        const int bufF = (k & 1) * PLANE_F;

        // commit plane k (regs -> LDS)
        *(float4*)&lds[bufF + le[0]] = r0;
        *(float4*)&lds[bufF + le[1]] = r1;
        if (has3) *(float4*)&lds[bufF + le[2]] = r2;
        __syncthreads();

        // prefetch plane k+1 (latency hidden under fold+compute below)
        {
            int yn = ybase + k;
            yn = yn > NN - 1 ? NN - 1 : yn;
            const int yr = yn * NN;
            r0 = *(const float4*)(sp[0] + gi[0] + yr);
            r1 = *(const float4*)(sp[1] + gi[1] + yr);
            if (has3) r2 = *(const float4*)(sp[2] + gi[2] + yr);
        }
        // prefetch mask for next step's compute (y = ybase+k-1)
        float4 m_next;
        {
            int my = ybase + k - 1;
            my = my < 0 ? 0 : (my > NN - 1 ? NN - 1 : my);
            m_next = *(const float4*)(M + (z * NN + my) * NN + x0);
        }

        // fold plane k into slot s = k%3
        const int s = k % 3;
#pragma unroll
        for (int arr = 0; arr < 2; ++arr) {
            float fa[4] = {0.f, 0.f, 0.f, 0.f};
            float fb[4] = {0.f, 0.f, 0.f, 0.f};
            float blo[4], bhi[4];
#pragma unroll
            for (int dz = 0; dz < 3; ++dz) {
                const int rb = bufF + arr * (ROWS * NN) + (tz + dz) * NN;
                const float4 c = *(const float4*)&lds[rb + x0];
                const float L = lds[rb + xm];
                const float R = lds[rb + xp];
                const float w[6] = {L, c.x, c.y, c.z, c.w, R};
#pragma unroll
                for (int i = 0; i < 4; ++i) {
                    const float a = w[i + 2] - w[i];
                    const float b = w[i] + w[i + 1] + w[i + 2];
                    fa[i] += a;
                    fb[i] += b;
                    if (dz == 0) blo[i] = b;
                    if (dz == 2) bhi[i] = b;
                }
            }
#pragma unroll
            for (int i = 0; i < 4; ++i) {
                sa[arr][s][i] = fa[i];
                sb[arr][s][i] = fb[i];
                tb[arr][s][i] = bhi[i] - blo[i];
            }
        }

        // compute voxel row y = ybase + k - 2 (slots y-1,y,y+1 live)
        if (k >= 2) {
            const int sA = (k - 2) % 3, sB = (k - 1) % 3, sC = k % 3;
            const float mm[4] = {m_cur.x, m_cur.y, m_cur.z, m_cur.w};
#pragma unroll
            for (int i = 0; i < 4; ++i) {
                const float Ix = sa[0][sA][i] + sa[0][sB][i] + sa[0][sC][i];
                const float Iy = sb[0][sC][i] - sb[0][sA][i];
                const float Iz = tb[0][sA][i] + tb[0][sB][i] + tb[0][sC][i];
                const float Jx = sa[1][sA][i] + sa[1][sB][i] + sa[1][sC][i];
                const float Jy = sb[1][sC][i] - sb[1][sA][i];
                const float Jz = tb[1][sA][i] + tb[1][sB][i] + tb[1][sC][i];
                const float im = Ix * Ix + Iy * Iy + Iz * Iz + 0.04f;
                const float jm = Jx * Jx + Jy * Jy + Jz * Jz + 0.04f;
                const float dot = Ix * Jx + Iy * Jy + Iz * Jz;
                acc += (1.0f - (dot * dot) / (im * jm)) * mm[i];
            }
        }
        m_cur = m_next;
        // no second barrier: write(k+2) to this buffer is separated from
        // read(k) by the barrier inside iteration k+1.
    }

    // mean scaling, then wave -> block -> global reduction
    acc *= (1.0f / ((float)NN * (float)NN * (float)NN));
#pragma unroll
    for (int off = 32; off > 0; off >>= 1)
        acc += __shfl_down(acc, off, 64);

    __shared__ float red[NTHR / 64];
    if ((flat & 63) == 0) red[flat >> 6] = acc;
    __syncthreads();
    if (flat == 0) {
        float ssum = 0.0f;
#pragma unroll
        for (int w = 0; w < NTHR / 64; ++w) ssum += red[w];
        atomicAdd(out, ssum);
    }
}

extern "C" void kernel_launch(void* const* d_in, const int* in_sizes, int n_in,
                              void* d_out, int out_size, void* d_ws, size_t ws_size,
                              hipStream_t stream) {
    const float* I = (const float*)d_in[0];
    const float* J = (const float*)d_in[1];
    const float* M = (const float*)d_in[2];
    float* out = (float*)d_out;

    hipMemsetAsync(d_out, 0, sizeof(float), stream);

    dim3 block(BX, BZ);               // 384 threads = 6 waves
    dim3 grid(NN / YC, NN / BZ);      // (24, 24) = 576 blocks
    ngf_kernel<<<grid, block, 0, stream>>>(I, J, M, out);
}

// Round 4
// 130.314 us; speedup vs baseline: 1.5638x; 1.5638x over previous
//
#include <hip/hip_runtime.h>

#define NN 192
#define BX 48
#define BZ 4
#define YC 8
#define NTHR (BX * BZ)

// Raw rows for one y-plane: rows 0..2 = I at z-1,z,z+1 ; rows 3..5 = J.
// c = float4 at x0 ; L/R = clamped edge scalars (x0-1, x0+4).
struct Raw {
    float4 c[6];
    float  L[6];
    float  R[6];
};

__device__ __forceinline__ void load_plane(const float* const base[6], int yrow,
                                           int dL, int dR, Raw& r) {
#pragma unroll
    for (int d = 0; d < 6; ++d) {
        const float* p = base[d] + yrow;
        r.c[d] = *reinterpret_cast<const float4*>(p);
        r.L[d] = p[dL];
        r.R[d] = p[dR];
    }
}

// Fold a z-triple of rows into slot quantities:
//   sa[i] = sum_dz (w[i+2]-w[i])        (x-diff summed over z  -> Ix)
//   sb[i] = sum_dz (w[i]+w[i+1]+w[i+2]) (x-box  summed over z  -> Iy)
//   tb[i] = xbox(z+1) - xbox(z-1)                              (-> Iz)
__device__ __forceinline__ void fold_rows(const float4& cm, float Lm, float Rm,
                                          const float4& c0, float L0, float R0,
                                          const float4& cp, float Lp, float Rp,
                                          float sa[4], float sb[4], float tb[4]) {
    const float wm[6] = {Lm, cm.x, cm.y, cm.z, cm.w, Rm};
    const float w0[6] = {L0, c0.x, c0.y, c0.z, c0.w, R0};
    const float wp[6] = {Lp, cp.x, cp.y, cp.z, cp.w, Rp};
#pragma unroll
    for (int i = 0; i < 4; ++i) {
        const float am = wm[i + 2] - wm[i];
        const float a0 = w0[i + 2] - w0[i];
        const float ap = wp[i + 2] - wp[i];
        const float bm = wm[i] + wm[i + 1] + wm[i + 2];
        const float b0 = w0[i] + w0[i + 1] + w0[i + 2];
        const float bp = wp[i] + wp[i + 1] + wp[i + 2];
        sa[i] = am + a0 + ap;
        sb[i] = bm + b0 + bp;
        tb[i] = bp - bm;
    }
}

// Raw (un-halved) gradients: rawG = 2*trueG; the 0.5^2 factors cancel in ngf
// when EPS^2 (0.01) is replaced by 4*EPS^2 = 0.04.
// __launch_bounds__(192,2): allow ~256 VGPRs so the 18 prefetch loads for the
// NEXT y-plane stay in flight across this step's fold+NGF (latency hiding by
// structure, not residency).
__global__ __launch_bounds__(NTHR, 2) void ngf_kernel(const float* __restrict__ I,
                                                      const float* __restrict__ J,
                                                      const float* __restrict__ M,
                                                      float* __restrict__ out) {
    const int tx = threadIdx.x;
    const int tz = threadIdx.y;
    const int x0 = tx * 4;
    const int dL = (tx == 0) ? 0 : -1;          // offset of clamped x0-1 from x0
    const int dR = (tx == BX - 1) ? 3 : 4;      // offset of clamped x0+4 from x0
    const int z = blockIdx.y * BZ + tz;
    const int ybase = blockIdx.x * YC;

    const int gzm = (z == 0) ? 0 : z - 1;
    const int gzp = (z == NN - 1) ? (NN - 1) : z + 1;

    const float* base[6] = {
        I + gzm * NN * NN + x0, I + z * NN * NN + x0, I + gzp * NN * NN + x0,
        J + gzm * NN * NN + x0, J + z * NN * NN + x0, J + gzp * NN * NN + x0};

    float sa[2][3][4], sb[2][3][4], tb[2][3][4];
    Raw A, B;

    // ---- seed: planes j=0 (gy = ybase-1, clamped) and j=1 (gy = ybase)
    load_plane(base, ((ybase == 0) ? 0 : (ybase - 1)) * NN, dL, dR, A);
    load_plane(base, ybase * NN, dL, dR, B);
    fold_rows(A.c[0], A.L[0], A.R[0], A.c[1], A.L[1], A.R[1], A.c[2], A.L[2], A.R[2],
              sa[0][0], sb[0][0], tb[0][0]);
    fold_rows(A.c[3], A.L[3], A.R[3], A.c[4], A.L[4], A.R[4], A.c[5], A.L[5], A.R[5],
              sa[1][0], sb[1][0], tb[1][0]);
    fold_rows(B.c[0], B.L[0], B.R[0], B.c[1], B.L[1], B.R[1], B.c[2], B.L[2], B.R[2],
              sa[0][1], sb[0][1], tb[0][1]);
    fold_rows(B.c[3], B.L[3], B.R[3], B.c[4], B.L[4], B.R[4], B.c[5], B.L[5], B.R[5],
              sa[1][1], sb[1][1], tb[1][1]);
    // prefetch plane j=2 (gy = ybase+1, always <= 185 < 192) and mask(ybase)
    load_plane(base, (ybase + 1) * NN, dL, dR, A);
    float4 mcur = *reinterpret_cast<const float4*>(M + (z * NN + ybase) * NN + x0);

    float acc = 0.0f;
#pragma unroll
    for (int yy = 0; yy < YC; ++yy) {
        const int j = yy + 2;                 // plane index of the raw buffer to fold
        Raw& cur = (yy & 1) ? B : A;          // constant under unroll
        Raw& nxt = (yy & 1) ? A : B;

        // 1) issue next plane's 18 loads + next mask (consumed next iteration)
        float4 mnxt = mcur;
        if (yy < YC - 1) {
            int gy = ybase + yy + 2;
            gy = (gy > NN - 1) ? (NN - 1) : gy;
            load_plane(base, gy * NN, dL, dR, nxt);
            mnxt = *reinterpret_cast<const float4*>(M + (z * NN + (ybase + yy + 1)) * NN + x0);
        }

        // 2) fold current raw plane (loads issued one full step ago)
        const int sC = j % 3;
        fold_rows(cur.c[0], cur.L[0], cur.R[0], cur.c[1], cur.L[1], cur.R[1],
                  cur.c[2], cur.L[2], cur.R[2], sa[0][sC], sb[0][sC], tb[0][sC]);
        fold_rows(cur.c[3], cur.L[3], cur.R[3], cur.c[4], cur.L[4], cur.R[4],
                  cur.c[5], cur.L[5], cur.R[5], sa[1][sC], sb[1][sC], tb[1][sC]);

        // 3) NGF at y = ybase+yy (slots yy, yy+1, yy+2 live)
        const int s0 = yy % 3, s1 = (yy + 1) % 3;
        const float mm[4] = {mcur.x, mcur.y, mcur.z, mcur.w};
#pragma unroll
        for (int i = 0; i < 4; ++i) {
            const float Ix = sa[0][s0][i] + sa[0][s1][i] + sa[0][sC][i];
            const float Iy = sb[0][sC][i] - sb[0][s0][i];
            const float Iz = tb[0][s0][i] + tb[0][s1][i] + tb[0][sC][i];
            const float Jx = sa[1][s0][i] + sa[1][s1][i] + sa[1][sC][i];
            const float Jy = sb[1][sC][i] - sb[1][s0][i];
            const float Jz = tb[1][s0][i] + tb[1][s1][i] + tb[1][sC][i];
            const float im = Ix * Ix + Iy * Iy + Iz * Iz + 0.04f;
            const float jm = Jx * Jx + Jy * Jy + Jz * Jz + 0.04f;
            const float dot = Ix * Jx + Iy * Jy + Iz * Jz;
            acc += (1.0f - (dot * dot) / (im * jm)) * mm[i];
        }
        mcur = mnxt;
    }

    // mean scaling, then wave -> block -> global reduction
    acc *= (1.0f / ((float)NN * (float)NN * (float)NN));
#pragma unroll
    for (int off = 32; off > 0; off >>= 1)
        acc += __shfl_down(acc, off, 64);

    __shared__ float red[NTHR / 64];
    const int flat = tz * BX + tx;
    if ((flat & 63) == 0) red[flat >> 6] = acc;
    __syncthreads();
    if (flat == 0) {
        float s = 0.0f;
#pragma unroll
        for (int w = 0; w < NTHR / 64; ++w) s += red[w];
        atomicAdd(out, s);
    }
}

extern "C" void kernel_launch(void* const* d_in, const int* in_sizes, int n_in,
                              void* d_out, int out_size, void* d_ws, size_t ws_size,
                              hipStream_t stream) {
    const float* I = (const float*)d_in[0];
    const float* J = (const float*)d_in[1];
    const float* M = (const float*)d_in[2];
    float* out = (float*)d_out;

    hipMemsetAsync(d_out, 0, sizeof(float), stream);

    dim3 block(BX, BZ);               // 192 threads = 3 waves
    dim3 grid(NN / YC, NN / BZ);      // (24, 48) = 1152 blocks
    ngf_kernel<<<grid, block, 0, stream>>>(I, J, M, out);
}

// Round 5
// 118.447 us; speedup vs baseline: 1.7204x; 1.1002x over previous
//
#include <hip/hip_runtime.h>

#define NN 192
#define BZ 4
#define YC 8
#define NTHR (64 * BZ)

// x is mapped across the 64 lanes of a wave, 3 floats per lane:
// lane l owns x = 3l .. 3l+2; a whole wave = one full x-row (192).
// The x-halo (x-1 / x+3) comes from neighbor lanes via shuffle.

// One row: given the lane's 3 values, produce
//   a[i] = w[x+1] - w[x-1]   (x-diff)
//   b[i] = w[x-1]+w[x]+w[x+1] (x-box), i = 0..2, with edge clamp at x=0/191.
__device__ __forceinline__ void row_ab(float c0, float c1, float c2, int lane,
                                       float a[3], float b[3]) {
    float L = __shfl_up(c2, 1, 64);    // neighbor lane-1's last element = x-1
    float R = __shfl_down(c0, 1, 64);  // neighbor lane+1's first element = x+3
    if (lane == 0)  L = c0;            // clamp x=-1 -> 0
    if (lane == 63) R = c2;            // clamp x=192 -> 191
    a[0] = c1 - L;
    a[1] = c2 - c0;
    a[2] = R - c1;
    b[0] = L + c0 + c1;
    b[1] = c0 + c1 + c2;
    b[2] = c1 + c2 + R;
}

// Fold one y-plane of one array (rows at z-1,z,z+1) into slot quantities:
//   sa = sum_dz a   (-> Ix),  sb = sum_dz b  (-> Iy),  tb = b(z+1)-b(z-1) (-> Iz)
__device__ __forceinline__ void fold_plane(const float3 r[3], int lane,
                                           float sa[3], float sb[3], float tb[3]) {
    float am[3], bm[3], a0[3], b0[3], ap[3], bp[3];
    row_ab(r[0].x, r[0].y, r[0].z, lane, am, bm);
    row_ab(r[1].x, r[1].y, r[1].z, lane, a0, b0);
    row_ab(r[2].x, r[2].y, r[2].z, lane, ap, bp);
#pragma unroll
    for (int i = 0; i < 3; ++i) {
        sa[i] = am[i] + a0[i] + ap[i];
        sb[i] = bm[i] + b0[i] + bp[i];
        tb[i] = bp[i] - bm[i];
    }
}

__device__ __forceinline__ void load_plane(const float* const base[6], int yrow,
                                           float3 rI[3], float3 rJ[3]) {
#pragma unroll
    for (int d = 0; d < 3; ++d) rI[d] = *reinterpret_cast<const float3*>(base[d] + yrow);
#pragma unroll
    for (int d = 0; d < 3; ++d) rJ[d] = *reinterpret_cast<const float3*>(base[3 + d] + yrow);
}

// Raw (un-halved) gradients: rawG = 2*trueG; the 0.5^2 factors cancel in ngf
// when EPS^2 (0.01) is replaced by 4*EPS^2 = 0.04.
__global__ __launch_bounds__(NTHR, 2) void ngf_kernel(const float* __restrict__ I,
                                                      const float* __restrict__ J,
                                                      const float* __restrict__ M,
                                                      float* __restrict__ out) {
    const int lane = threadIdx.x;         // 0..63
    const int tz = threadIdx.y;
    const int xoff = lane * 3;
    const int z = blockIdx.y * BZ + tz;
    const int ybase = blockIdx.x * YC;

    const int gzm = (z == 0) ? 0 : z - 1;
    const int gzp = (z == NN - 1) ? (NN - 1) : z + 1;

    const float* base[6] = {
        I + gzm * NN * NN + xoff, I + z * NN * NN + xoff, I + gzp * NN * NN + xoff,
        J + gzm * NN * NN + xoff, J + z * NN * NN + xoff, J + gzp * NN * NN + xoff};
    const float* mbase = M + z * NN * NN + xoff;

    float sa[2][3][3], sb[2][3][3], tb[2][3][3];

    // ---- seed: fold plane y=ybase-1 (clamped) into slot 0, y=ybase into slot 1
    {
        float3 rI[3], rJ[3];
        load_plane(base, ((ybase == 0) ? 0 : (ybase - 1)) * NN, rI, rJ);
        fold_plane(rI, lane, sa[0][0], sb[0][0], tb[0][0]);
        fold_plane(rJ, lane, sa[1][0], sb[1][0], tb[1][0]);
        load_plane(base, ybase * NN, rI, rJ);
        fold_plane(rI, lane, sa[0][1], sb[0][1], tb[0][1]);
        fold_plane(rJ, lane, sa[1][1], sb[1][1], tb[1][1]);
    }

    // raw-plane double buffer (18+18 floats) + mask; prefetch plane ybase+1
    float3 bI[2][3], bJ[2][3];
    load_plane(base, (ybase + 1) * NN, bI[0], bJ[0]);   // ybase+1 <= 185
    float3 mcur = *reinterpret_cast<const float3*>(mbase + ybase * NN);

    float acc = 0.0f;
#pragma unroll
    for (int yy = 0; yy < YC; ++yy) {
        const int cb = yy & 1, nb = cb ^ 1;   // constant after unroll

        // 1) issue next plane's 7 loads (consumed next iteration)
        float3 mnxt = mcur;
        if (yy < YC - 1) {
            int gy = ybase + yy + 2;
            gy = (gy > NN - 1) ? (NN - 1) : gy;
            load_plane(base, gy * NN, bI[nb], bJ[nb]);
            mnxt = *reinterpret_cast<const float3*>(mbase + (ybase + yy + 1) * NN);
        }

        // 2) fold plane y = ybase+yy+1 (its loads were issued one step ago)
        const int sC = (yy + 2) % 3;
        fold_plane(bI[cb], lane, sa[0][sC], sb[0][sC], tb[0][sC]);
        fold_plane(bJ[cb], lane, sa[1][sC], sb[1][sC], tb[1][sC]);

        // 3) NGF at y = ybase+yy (slots yy, yy+1, yy+2 live)
        const int s0 = yy % 3, s1 = (yy + 1) % 3;
        const float mm[3] = {mcur.x, mcur.y, mcur.z};
#pragma unroll
        for (int i = 0; i < 3; ++i) {
            const float Ix = sa[0][s0][i] + sa[0][s1][i] + sa[0][sC][i];
            const float Iy = sb[0][sC][i] - sb[0][s0][i];
            const float Iz = tb[0][s0][i] + tb[0][s1][i] + tb[0][sC][i];
            const float Jx = sa[1][s0][i] + sa[1][s1][i] + sa[1][sC][i];
            const float Jy = sb[1][sC][i] - sb[1][s0][i];
            const float Jz = tb[1][s0][i] + tb[1][s1][i] + tb[1][sC][i];
            const float im = Ix * Ix + Iy * Iy + Iz * Iz + 0.04f;
            const float jm = Jx * Jx + Jy * Jy + Jz * Jz + 0.04f;
            const float dot = Ix * Jx + Iy * Jy + Iz * Jz;
            acc += (1.0f - dot * dot * __builtin_amdgcn_rcpf(im * jm)) * mm[i];
        }
        mcur = mnxt;
    }

    // mean scaling, then wave -> block -> global reduction
    acc *= (1.0f / ((float)NN * (float)NN * (float)NN));
#pragma unroll
    for (int off = 32; off > 0; off >>= 1)
        acc += __shfl_down(acc, off, 64);

    __shared__ float red[NTHR / 64];
    const int flat = tz * 64 + lane;
    if ((flat & 63) == 0) red[flat >> 6] = acc;
    __syncthreads();
    if (flat == 0) {
        float s = 0.0f;
#pragma unroll
        for (int w = 0; w < NTHR / 64; ++w) s += red[w];
        atomicAdd(out, s);
    }
}

extern "C" void kernel_launch(void* const* d_in, const int* in_sizes, int n_in,
                              void* d_out, int out_size, void* d_ws, size_t ws_size,
                              hipStream_t stream) {
    const float* I = (const float*)d_in[0];
    const float* J = (const float*)d_in[1];
    const float* M = (const float*)d_in[2];
    float* out = (float*)d_out;

    hipMemsetAsync(d_out, 0, sizeof(float), stream);

    dim3 block(64, BZ);               // 256 threads = 4 waves
    dim3 grid(NN / YC, NN / BZ);      // (24, 48) = 1152 blocks
    ngf_kernel<<<grid, block, 0, stream>>>(I, J, M, out);
}